// Round 2
// baseline (1935.461 us; speedup 1.0000x reference)
//
#include <hip/hip_runtime.h>
#include <hip/hip_bf16.h>

#define NN 100000
#define EE 1000000
#define FIN 15
#define HH 64
#define EMBD 128
#define RR 13
#define NBASE 4

typedef __hip_bfloat16 bf16;

__device__ __forceinline__ float b2f(bf16 x) { return __bfloat162float(x); }

// ---------- dtype auto-detect ----------
// W_in is Xavier-init with |w| <= sqrt(6/79) ~= 0.276. Read as bf16:
//  - if buffer truly bf16: zero elements with |v| >= 0.3
//  - if buffer truly fp32: the low-halfword of each float reads as a bf16 with
//    ~uniform exponent -> ~50% of elements have |v| >= 0.3 (or NaN).
// flag: 0 = tensors are bf16, 1 = tensors are fp32.
__global__ void k_detect(const void* __restrict__ win, int* __restrict__ flag) {
    int tid = threadIdx.x;  // 64 threads
    const bf16* p = (const bf16*)win;
    int cnt = 0;
    for (int i = tid; i < FIN * HH; i += 64) {
        float v = b2f(p[i]);
        if (!(fabsf(v) < 0.3f)) cnt++;  // counts NaN too
    }
#pragma unroll
    for (int off = 32; off > 0; off >>= 1) cnt += __shfl_down(cnt, off, 64);
    if (tid == 0) *flag = (cnt > 40) ? 1 : 0;
}

// convert one float-typed input tensor to fp32 in workspace
__global__ void k_convert(const void* __restrict__ in, float* __restrict__ out, int n,
                          const int* __restrict__ flag) {
    int i = blockIdx.x * 256 + threadIdx.x;
    if (i >= n) return;
    if (*flag) out[i] = ((const float*)in)[i];
    else       out[i] = b2f(((const bf16*)in)[i]);
}

// ---------- pipeline (all fp32 from here) ----------

// h0[n][j] = sum_k nf[n][k] * Win[k][j] + bin[j]
__global__ void k_input_proj(const float* __restrict__ nf, const float* __restrict__ Win,
                             const float* __restrict__ bin, float* __restrict__ h) {
    __shared__ float w[FIN * HH];
    __shared__ float bb[HH];
    int tid = threadIdx.x;
    for (int i = tid; i < FIN * HH; i += 256) w[i] = Win[i];
    if (tid < HH) bb[tid] = bin[tid];
    __syncthreads();
    int idx = blockIdx.x * 256 + tid;
    if (idx >= NN * HH) return;
    int n = idx >> 6, j = idx & 63;
    float acc = bb[j];
    const float* row = nf + n * FIN;
#pragma unroll
    for (int k = 0; k < FIN; ++k) acc = fmaf(row[k], w[k * HH + j], acc);
    h[idx] = acc;
}

// W_r = sum_b coeffs[r][b] * bases[b]   -> (R, H, H) fp32
__global__ void k_make_wr(const float* __restrict__ bases, const float* __restrict__ coeffs,
                          float* __restrict__ Wr) {
    int idx = blockIdx.x * 256 + threadIdx.x;
    if (idx >= RR * HH * HH) return;
    int r = idx / (HH * HH);
    int kj = idx - r * HH * HH;
    float acc = 0.f;
#pragma unroll
    for (int b = 0; b < NBASE; ++b)
        acc = fmaf(coeffs[r * NBASE + b], bases[b * HH * HH + kj], acc);
    Wr[idx] = acc;
}

// pre[n][j] = sum_k h[n][k] * Wself[k][j] + bself[j]
__global__ void k_self_mm(const float* __restrict__ h, const float* __restrict__ Wself,
                          const float* __restrict__ bself, float* __restrict__ pre) {
    __shared__ float w[HH * HH];
    __shared__ float bb[HH];
    int tid = threadIdx.x;
    for (int i = tid; i < HH * HH; i += 256) w[i] = Wself[i];
    if (tid < HH) bb[tid] = bself[tid];
    __syncthreads();
    int idx = blockIdx.x * 256 + tid;
    if (idx >= NN * HH) return;
    int n = idx >> 6, j = idx & 63;
    float acc = bb[j];
    const float* row = h + n * HH;
#pragma unroll 16
    for (int k = 0; k < HH; ++k) acc = fmaf(row[k], w[k * HH + j], acc);
    pre[idx] = acc;
}

// per edge: msg = h[src] @ W_r[etype]; atomicAdd into pre[tgt]
// one wave (64 lanes) per edge; lane j owns output column j
__global__ void k_edge(const float* __restrict__ h, const int* __restrict__ src,
                       const int* __restrict__ tgt, const int* __restrict__ et,
                       const float* __restrict__ Wr, float* __restrict__ pre) {
    int tid = threadIdx.x;
    int lane = tid & 63;
    int e = blockIdx.x * 4 + (tid >> 6);
    if (e >= EE) return;
    int s = src[e], t = tgt[e], r = et[e];
    float hk = h[s * HH + lane];             // coalesced 256B load of the src row
    const float* w = Wr + r * HH * HH + lane;
    float acc = 0.f;
#pragma unroll
    for (int k = 0; k < HH; ++k) {
        float hv = __shfl(hk, k, 64);        // broadcast h[src][k]
        acc = fmaf(hv, w[k * HH], acc);      // coalesced W_r row read (L1/L2 hit)
    }
    atomicAdd(&pre[t * HH + lane], acc);
}

__global__ void k_relu(float* __restrict__ x, int n) {
    int idx = blockIdx.x * 256 + threadIdx.x;
    if (idx < n) x[idx] = fmaxf(x[idx], 0.f);
}

// per-block partial sum & max over nodes, per column
__global__ void k_reduce(const float* __restrict__ h, float* __restrict__ psum,
                         float* __restrict__ pmax) {
    __shared__ float ls[256], lm[256];
    int tid = threadIdx.x;
    int j = tid & 63;
    int slot = tid >> 6;
    float s = 0.f, m = -1e30f;
    for (int n = blockIdx.x * 4 + slot; n < NN; n += gridDim.x * 4) {
        float v = h[n * HH + j];
        s += v;
        m = fmaxf(m, v);
    }
    ls[tid] = s; lm[tid] = m;
    __syncthreads();
    if (tid < 64) {
        s = ls[tid] + ls[tid + 64] + ls[tid + 128] + ls[tid + 192];
        m = fmaxf(fmaxf(lm[tid], lm[tid + 64]), fmaxf(lm[tid + 128], lm[tid + 192]));
        psum[blockIdx.x * 64 + tid] = s;
        pmax[blockIdx.x * 64 + tid] = m;
    }
}

// final reduce + readout MLP -> graph_emb (128 elems), dtype per flag
__global__ void k_final(const float* __restrict__ psum, const float* __restrict__ pmax,
                        int nblocks, const float* __restrict__ Wr1, const float* __restrict__ br1,
                        const float* __restrict__ Wr2, const float* __restrict__ br2,
                        void* __restrict__ out, const int* __restrict__ flag) {
    __shared__ float g[2 * HH];
    __shared__ float tbuf[HH];
    int tid = threadIdx.x;  // 128 threads
    if (tid < 64) {
        float s = 0.f, m = -1e30f;
        for (int i = 0; i < nblocks; ++i) {
            s += psum[i * 64 + tid];
            m = fmaxf(m, pmax[i * 64 + tid]);
        }
        g[tid] = s * (1.0f / NN);
        g[64 + tid] = m;
    }
    __syncthreads();
    if (tid < 64) {
        float acc = br1[tid];
        for (int k = 0; k < 2 * HH; ++k) acc = fmaf(g[k], Wr1[k * HH + tid], acc);
        tbuf[tid] = fmaxf(acc, 0.f);
    }
    __syncthreads();
    float acc = br2[tid];
    for (int k = 0; k < HH; ++k) acc = fmaf(tbuf[k], Wr2[k * EMBD + tid], acc);
    if (*flag) ((float*)out)[tid] = acc;
    else       ((bf16*)out)[tid] = __float2bfloat16(acc);
}

// node_emb[n][j] = sum_k h[n][k] * Wnp[k][j] + bnp[j] -> out elements [EMBD, EMBD+N*EMBD)
__global__ void k_node_emb(const float* __restrict__ h, const float* __restrict__ Wnp,
                           const float* __restrict__ bnp, void* __restrict__ out,
                           const int* __restrict__ flag) {
    __shared__ float w[HH * EMBD];
    __shared__ float bb[EMBD];
    int tid = threadIdx.x;
    for (int i = tid; i < HH * EMBD; i += 256) w[i] = Wnp[i];
    if (tid < EMBD) bb[tid] = bnp[tid];
    __syncthreads();
    int idx = blockIdx.x * 256 + tid;
    if (idx >= NN * EMBD) return;
    int n = idx >> 7, j = idx & 127;
    float acc = bb[j];
    const float* row = h + n * HH;
#pragma unroll 16
    for (int k = 0; k < HH; ++k) acc = fmaf(row[k], w[k * EMBD + j], acc);
    if (*flag) ((float*)out)[EMBD + idx] = acc;
    else       ((bf16*)out)[EMBD + idx] = __float2bfloat16(acc);
}

extern "C" void kernel_launch(void* const* d_in, const int* in_sizes, int n_in,
                              void* d_out, int out_size, void* d_ws, size_t ws_size,
                              hipStream_t stream) {
    const int* eidx  = (const int*)d_in[1];
    const int* etype = (const int*)d_in[2];
    const int* src = eidx;
    const int* tgt = eidx + EE;

    // ---- workspace layout ----
    int* flag = (int*)d_ws;
    float* p = (float*)d_ws + 16;

    // indices of float-typed inputs, in order
    const int fidx[17] = {0, 3, 4, 5, 6, 7, 8, 9, 10, 11, 12, 13, 14, 15, 16, 17, 18};
    float* conv[19];

    k_detect<<<1, 64, 0, stream>>>(d_in[3], flag);

    for (int t = 0; t < 17; ++t) {
        int i = fidx[t];
        int n = in_sizes[i];
        conv[i] = p;
        k_convert<<<(n + 255) / 256, 256, 0, stream>>>(d_in[i], p, n, flag);
        p += (n + 15) & ~15;  // keep 64B alignment
    }

    float* hA   = p;                    p += NN * HH;
    float* hB   = p;                    p += NN * HH;
    float* Wr   = p;                    p += RR * HH * HH;
    float* psum = p;                    p += 256 * 64;
    float* pmax = p;                    p += 256 * 64;

    const float* nf      = conv[0];
    const float* Win     = conv[3];
    const float* bin     = conv[4];
    const float* Wself0  = conv[5];
    const float* bself0  = conv[6];
    const float* bases0  = conv[7];
    const float* coeffs0 = conv[8];
    const float* Wself1  = conv[9];
    const float* bself1  = conv[10];
    const float* bases1  = conv[11];
    const float* coeffs1 = conv[12];
    const float* Wr1     = conv[13];
    const float* br1     = conv[14];
    const float* Wr2     = conv[15];
    const float* br2     = conv[16];
    const float* Wnp     = conv[17];
    const float* bnp     = conv[18];

    const int NHB = (NN * HH) / 256;     // 25000
    const int WRB = (RR * HH * HH + 255) / 256;

    k_input_proj<<<NHB, 256, 0, stream>>>(nf, Win, bin, hA);

    // layer 0: hB = relu(hA@Wself0 + bself0 + scatter(hA@W_r))
    k_make_wr<<<WRB, 256, 0, stream>>>(bases0, coeffs0, Wr);
    k_self_mm<<<NHB, 256, 0, stream>>>(hA, Wself0, bself0, hB);
    k_edge<<<EE / 4, 256, 0, stream>>>(hA, src, tgt, etype, Wr, hB);
    k_relu<<<NHB, 256, 0, stream>>>(hB, NN * HH);

    // layer 1: hA = relu(hB@Wself1 + bself1 + scatter(hB@W_r))
    k_make_wr<<<WRB, 256, 0, stream>>>(bases1, coeffs1, Wr);
    k_self_mm<<<NHB, 256, 0, stream>>>(hB, Wself1, bself1, hA);
    k_edge<<<EE / 4, 256, 0, stream>>>(hB, src, tgt, etype, Wr, hA);
    k_relu<<<NHB, 256, 0, stream>>>(hA, NN * HH);

    // readout
    k_reduce<<<256, 256, 0, stream>>>(hA, psum, pmax);
    k_final<<<1, 128, 0, stream>>>(psum, pmax, 256, Wr1, br1, Wr2, br2, d_out, flag);
    k_node_emb<<<(NN * EMBD) / 256, 256, 0, stream>>>(hA, Wnp, bnp, d_out, flag);
}

// Round 3
// 1254.288 us; speedup vs baseline: 1.5431x; 1.5431x over previous
//
#include <hip/hip_runtime.h>
#include <hip/hip_bf16.h>

#define NN 100000
#define EE 1000000
#define FIN 15
#define HH 64
#define EMBD 128
#define RR 13
#define NBASE 4

typedef __hip_bfloat16 bf16;

__device__ __forceinline__ float b2f(bf16 x) { return __bfloat162float(x); }

// ---------- dtype auto-detect (see round-2 notes) ----------
__global__ void k_detect(const void* __restrict__ win, int* __restrict__ flag) {
    int tid = threadIdx.x;  // 64 threads
    const bf16* p = (const bf16*)win;
    int cnt = 0;
    for (int i = tid; i < FIN * HH; i += 64) {
        float v = b2f(p[i]);
        if (!(fabsf(v) < 0.3f)) cnt++;  // counts NaN too
    }
#pragma unroll
    for (int off = 32; off > 0; off >>= 1) cnt += __shfl_down(cnt, off, 64);
    if (tid == 0) *flag = (cnt > 40) ? 1 : 0;
}

// ---------- fused convert of all 17 float tensors ----------
struct ConvTab {
    const void* in[17];
    int n[17];
    int cum[18];   // padded cumulative float offsets (== placement offsets)
};

__global__ void k_convert_all(ConvTab tab, float* __restrict__ base,
                              const int* __restrict__ flag) {
    int g = blockIdx.x * 256 + threadIdx.x;
    if (g >= tab.cum[17]) return;
    int t = 0;
#pragma unroll
    for (int i = 0; i < 17; ++i) if (g >= tab.cum[i + 1]) t = i + 1;
    int local = g - tab.cum[t];
    if (local >= tab.n[t]) return;  // padding gap
    float v;
    if (*flag) v = ((const float*)tab.in[t])[local];
    else       v = b2f(((const bf16*)tab.in[t])[local]);
    base[g] = v;
}

// ---------- pipeline (fp32) ----------

__global__ void k_input_proj(const float* __restrict__ nf, const float* __restrict__ Win,
                             const float* __restrict__ bin, float* __restrict__ h) {
    __shared__ float w[FIN * HH];
    __shared__ float bb[HH];
    int tid = threadIdx.x;
    for (int i = tid; i < FIN * HH; i += 256) w[i] = Win[i];
    if (tid < HH) bb[tid] = bin[tid];
    __syncthreads();
    int idx = blockIdx.x * 256 + tid;
    if (idx >= NN * HH) return;
    int n = idx >> 6, j = idx & 63;
    float acc = bb[j];
    const float* row = nf + n * FIN;
#pragma unroll
    for (int k = 0; k < FIN; ++k) acc = fmaf(row[k], w[k * HH + j], acc);
    h[idx] = acc;
}

// hbX[n][b*64+j] = sum_k h[n][k] * bases[b][k][j]    (NPB nodes per block)
#define NPB 16
__global__ void k_hb(const float* __restrict__ h, const float* __restrict__ bases,
                     float* __restrict__ hbX) {
    __shared__ float bs[NBASE * HH * HH];   // 64 KB
    __shared__ float hrow[NPB][HH];         // 4 KB
    int tid = threadIdx.x;
    for (int i = tid; i < NBASE * HH * HH; i += 256) bs[i] = bases[i];
    int n0 = blockIdx.x * NPB;
    for (int i = tid; i < NPB * HH; i += 256) hrow[i >> 6][i & 63] = h[n0 * HH + i];
    __syncthreads();
    int b = tid >> 6, j = tid & 63;
    float acc[NPB];
#pragma unroll
    for (int ln = 0; ln < NPB; ++ln) acc[ln] = 0.f;
    const float* wb = bs + b * HH * HH + j;
#pragma unroll 8
    for (int k = 0; k < HH; ++k) {
        float w = wb[k * HH];               // 256B/wave, conflict-free
#pragma unroll
        for (int ln = 0; ln < NPB; ++ln)
            acc[ln] = fmaf(hrow[ln][k], w, acc[ln]);  // broadcast read
    }
#pragma unroll
    for (int ln = 0; ln < NPB; ++ln)
        hbX[(long)(n0 + ln) * (NBASE * HH) + b * HH + j] = acc[ln];
}

__global__ void k_self_mm(const float* __restrict__ h, const float* __restrict__ Wself,
                          const float* __restrict__ bself, float* __restrict__ pre) {
    __shared__ float w[HH * HH];
    __shared__ float bb[HH];
    int tid = threadIdx.x;
    for (int i = tid; i < HH * HH; i += 256) w[i] = Wself[i];
    if (tid < HH) bb[tid] = bself[tid];
    __syncthreads();
    int idx = blockIdx.x * 256 + tid;
    if (idx >= NN * HH) return;
    int n = idx >> 6, j = idx & 63;
    float acc = bb[j];
    const float* row = h + n * HH;
#pragma unroll 16
    for (int k = 0; k < HH; ++k) acc = fmaf(row[k], w[k * HH + j], acc);
    pre[idx] = acc;
}

// v2 edge kernel: msg[j] = sum_b coeffs[et][b] * hbX[src][b*64+j]
#define EPW 8   // edges per wave
__global__ void k_edge2(const float* __restrict__ hbX, const int* __restrict__ src,
                        const int* __restrict__ tgt, const int* __restrict__ et,
                        const float* __restrict__ coeffs, float* __restrict__ pre) {
    int lane = threadIdx.x & 63;
    int wid = (blockIdx.x * 256 + threadIdx.x) >> 6;
    int e0 = wid * EPW;
#pragma unroll
    for (int i = 0; i < EPW; ++i) {
        int e = e0 + i;
        if (e >= EE) return;
        int s = src[e], t = tgt[e], r = et[e];
        const float* row = hbX + (long)s * (NBASE * HH);
        const float* c = coeffs + r * NBASE;
        float m = c[0] * row[lane];
        m = fmaf(c[1], row[HH + lane], m);
        m = fmaf(c[2], row[2 * HH + lane], m);
        m = fmaf(c[3], row[3 * HH + lane], m);
        atomicAdd(&pre[(long)t * HH + lane], m);
    }
}

// v1 fallback: W_r = sum_b coeffs[r][b]*bases[b]
__global__ void k_make_wr(const float* __restrict__ bases, const float* __restrict__ coeffs,
                          float* __restrict__ Wr) {
    int idx = blockIdx.x * 256 + threadIdx.x;
    if (idx >= RR * HH * HH) return;
    int r = idx / (HH * HH);
    int kj = idx - r * HH * HH;
    float acc = 0.f;
#pragma unroll
    for (int b = 0; b < NBASE; ++b)
        acc = fmaf(coeffs[r * NBASE + b], bases[b * HH * HH + kj], acc);
    Wr[idx] = acc;
}

// v1 fallback edge kernel (one wave per edge, W_r matvec)
__global__ void k_edge(const float* __restrict__ h, const int* __restrict__ src,
                       const int* __restrict__ tgt, const int* __restrict__ et,
                       const float* __restrict__ Wr, float* __restrict__ pre) {
    int tid = threadIdx.x;
    int lane = tid & 63;
    int e = blockIdx.x * 4 + (tid >> 6);
    if (e >= EE) return;
    int s = src[e], t = tgt[e], r = et[e];
    float hk = h[s * HH + lane];
    const float* w = Wr + r * HH * HH + lane;
    float acc = 0.f;
#pragma unroll
    for (int k = 0; k < HH; ++k) {
        float hv = __shfl(hk, k, 64);
        acc = fmaf(hv, w[k * HH], acc);
    }
    atomicAdd(&pre[(long)t * HH + lane], acc);
}

__global__ void k_relu(float* __restrict__ x, int n) {
    int idx = blockIdx.x * 256 + threadIdx.x;
    if (idx < n) x[idx] = fmaxf(x[idx], 0.f);
}

__global__ void k_reduce(const float* __restrict__ h, float* __restrict__ psum,
                         float* __restrict__ pmax) {
    __shared__ float ls[256], lm[256];
    int tid = threadIdx.x;
    int j = tid & 63;
    int slot = tid >> 6;
    float s = 0.f, m = -1e30f;
    for (int n = blockIdx.x * 4 + slot; n < NN; n += gridDim.x * 4) {
        float v = h[n * HH + j];
        s += v;
        m = fmaxf(m, v);
    }
    ls[tid] = s; lm[tid] = m;
    __syncthreads();
    if (tid < 64) {
        s = ls[tid] + ls[tid + 64] + ls[tid + 128] + ls[tid + 192];
        m = fmaxf(fmaxf(lm[tid], lm[tid + 64]), fmaxf(lm[tid + 128], lm[tid + 192]));
        psum[blockIdx.x * 64 + tid] = s;
        pmax[blockIdx.x * 64 + tid] = m;
    }
}

__global__ void k_final(const float* __restrict__ psum, const float* __restrict__ pmax,
                        int nblocks, const float* __restrict__ Wr1, const float* __restrict__ br1,
                        const float* __restrict__ Wr2, const float* __restrict__ br2,
                        void* __restrict__ out, const int* __restrict__ flag) {
    __shared__ float g[2 * HH];
    __shared__ float tbuf[HH];
    int tid = threadIdx.x;  // 128 threads
    if (tid < 64) {
        float s = 0.f, m = -1e30f;
        for (int i = 0; i < nblocks; ++i) {
            s += psum[i * 64 + tid];
            m = fmaxf(m, pmax[i * 64 + tid]);
        }
        g[tid] = s * (1.0f / NN);
        g[64 + tid] = m;
    }
    __syncthreads();
    if (tid < 64) {
        float acc = br1[tid];
        for (int k = 0; k < 2 * HH; ++k) acc = fmaf(g[k], Wr1[k * HH + tid], acc);
        tbuf[tid] = fmaxf(acc, 0.f);
    }
    __syncthreads();
    float acc = br2[tid];
    for (int k = 0; k < HH; ++k) acc = fmaf(tbuf[k], Wr2[k * EMBD + tid], acc);
    if (*flag) ((float*)out)[tid] = acc;
    else       ((bf16*)out)[tid] = __float2bfloat16(acc);
}

__global__ void k_node_emb(const float* __restrict__ h, const float* __restrict__ Wnp,
                           const float* __restrict__ bnp, void* __restrict__ out,
                           const int* __restrict__ flag) {
    __shared__ float w[HH * EMBD];
    __shared__ float bb[EMBD];
    int tid = threadIdx.x;
    for (int i = tid; i < HH * EMBD; i += 256) w[i] = Wnp[i];
    if (tid < EMBD) bb[tid] = bnp[tid];
    __syncthreads();
    int idx = blockIdx.x * 256 + tid;
    if (idx >= NN * EMBD) return;
    int n = idx >> 7, j = idx & 127;
    float acc = bb[j];
    const float* row = h + n * HH;
#pragma unroll 16
    for (int k = 0; k < HH; ++k) acc = fmaf(row[k], w[k * EMBD + j], acc);
    if (*flag) ((float*)out)[EMBD + idx] = acc;
    else       ((bf16*)out)[EMBD + idx] = __float2bfloat16(acc);
}

extern "C" void kernel_launch(void* const* d_in, const int* in_sizes, int n_in,
                              void* d_out, int out_size, void* d_ws, size_t ws_size,
                              hipStream_t stream) {
    const int* eidx  = (const int*)d_in[1];
    const int* etype = (const int*)d_in[2];
    const int* src = eidx;
    const int* tgt = eidx + EE;

    int* flag = (int*)d_ws;
    float* base = (float*)d_ws + 16;

    const int fidx[17] = {0, 3, 4, 5, 6, 7, 8, 9, 10, 11, 12, 13, 14, 15, 16, 17, 18};
    ConvTab tab;
    float* conv[19];
    int cum = 0;
    for (int t = 0; t < 17; ++t) {
        int i = fidx[t];
        tab.in[t] = d_in[i];
        tab.n[t] = in_sizes[i];
        tab.cum[t] = cum;
        conv[i] = base + cum;
        cum += (in_sizes[i] + 15) & ~15;
    }
    tab.cum[17] = cum;

    k_detect<<<1, 64, 0, stream>>>(d_in[3], flag);
    k_convert_all<<<(cum + 255) / 256, 256, 0, stream>>>(tab, base, flag);

    float* p = base + cum;
    float* hA   = p;  p += NN * HH;
    float* hB   = p;  p += NN * HH;
    float* psum = p;  p += 256 * 64;
    float* pmax = p;  p += 256 * 64;
    float* big  = p;  // either hbX (N*256) or Wr (R*H*H)

    // bytes needed for the hbX path
    size_t need_v2 = (size_t)(16 + cum + 2 * NN * HH + 2 * 256 * 64
                              + (size_t)NN * NBASE * HH) * 4 + 64;
    bool use_v2 = ws_size >= need_v2;

    const float* nf      = conv[0];
    const float* Win     = conv[3];
    const float* bin     = conv[4];
    const float* Wself0  = conv[5];
    const float* bself0  = conv[6];
    const float* bases0  = conv[7];
    const float* coeffs0 = conv[8];
    const float* Wself1  = conv[9];
    const float* bself1  = conv[10];
    const float* bases1  = conv[11];
    const float* coeffs1 = conv[12];
    const float* Wr1     = conv[13];
    const float* br1     = conv[14];
    const float* Wr2     = conv[15];
    const float* br2     = conv[16];
    const float* Wnp     = conv[17];
    const float* bnp     = conv[18];

    const int NHB = (NN * HH) / 256;
    const int WRB = (RR * HH * HH + 255) / 256;
    const int EB2 = (EE + EPW * 4 - 1) / (EPW * 4);

    k_input_proj<<<NHB, 256, 0, stream>>>(nf, Win, bin, hA);

    if (use_v2) {
        // layer 0
        k_hb<<<NN / NPB, 256, 0, stream>>>(hA, bases0, big);
        k_self_mm<<<NHB, 256, 0, stream>>>(hA, Wself0, bself0, hB);
        k_edge2<<<EB2, 256, 0, stream>>>(big, src, tgt, etype, coeffs0, hB);
        k_relu<<<NHB, 256, 0, stream>>>(hB, NN * HH);
        // layer 1
        k_hb<<<NN / NPB, 256, 0, stream>>>(hB, bases1, big);
        k_self_mm<<<NHB, 256, 0, stream>>>(hB, Wself1, bself1, hA);
        k_edge2<<<EB2, 256, 0, stream>>>(big, src, tgt, etype, coeffs1, hA);
        k_relu<<<NHB, 256, 0, stream>>>(hA, NN * HH);
    } else {
        // fallback: round-2 structure
        k_make_wr<<<WRB, 256, 0, stream>>>(bases0, coeffs0, big);
        k_self_mm<<<NHB, 256, 0, stream>>>(hA, Wself0, bself0, hB);
        k_edge<<<EE / 4, 256, 0, stream>>>(hA, src, tgt, etype, big, hB);
        k_relu<<<NHB, 256, 0, stream>>>(hB, NN * HH);
        k_make_wr<<<WRB, 256, 0, stream>>>(bases1, coeffs1, big);
        k_self_mm<<<NHB, 256, 0, stream>>>(hB, Wself1, bself1, hA);
        k_edge<<<EE / 4, 256, 0, stream>>>(hB, src, tgt, etype, big, hA);
        k_relu<<<NHB, 256, 0, stream>>>(hA, NN * HH);
    }

    k_reduce<<<256, 256, 0, stream>>>(hA, psum, pmax);
    k_final<<<1, 128, 0, stream>>>(psum, pmax, 256, Wr1, br1, Wr2, br2, d_out, flag);
    k_node_emb<<<(NN * EMBD) / 256, 256, 0, stream>>>(hA, Wnp, bnp, d_out, flag);
}

// Round 4
// 890.330 us; speedup vs baseline: 2.1739x; 1.4088x over previous
//
#include <hip/hip_runtime.h>
#include <hip/hip_bf16.h>

#define NN 100000
#define EE 1000000
#define FIN 15
#define HH 64
#define EMBD 128
#define RR 13
#define NBASE 4

typedef __hip_bfloat16 bf16;

__device__ __forceinline__ float b2f(bf16 x) { return __bfloat162float(x); }

// VALU-pipe lane broadcast (v_readlane), avoids ds_bpermute
__device__ __forceinline__ float bcast(float v, int l) {
    return __uint_as_float(__builtin_amdgcn_readlane(__float_as_uint(v), l));
}
__device__ __forceinline__ unsigned short f2bu(float f) {
    bf16 t = __float2bfloat16(f);
    return *reinterpret_cast<unsigned short*>(&t);
}
__device__ __forceinline__ float bu2f(unsigned short u) {
    return __uint_as_float((unsigned)u << 16);  // bf16->f32 exact
}

// ---------- dtype auto-detect (see round-2 notes) ----------
__global__ void k_detect(const void* __restrict__ win, int* __restrict__ flag) {
    int tid = threadIdx.x;  // 64 threads
    const bf16* p = (const bf16*)win;
    int cnt = 0;
    for (int i = tid; i < FIN * HH; i += 64) {
        float v = b2f(p[i]);
        if (!(fabsf(v) < 0.3f)) cnt++;  // counts NaN too
    }
#pragma unroll
    for (int off = 32; off > 0; off >>= 1) cnt += __shfl_down(cnt, off, 64);
    if (tid == 0) *flag = (cnt > 40) ? 1 : 0;
}

// ---------- fused convert of all 17 float tensors ----------
struct ConvTab {
    const void* in[17];
    int n[17];
    int cum[18];
};

__global__ void k_convert_all(ConvTab tab, float* __restrict__ base,
                              const int* __restrict__ flag) {
    int g = blockIdx.x * 256 + threadIdx.x;
    if (g >= tab.cum[17]) return;
    int t = 0;
#pragma unroll
    for (int i = 0; i < 17; ++i) if (g >= tab.cum[i + 1]) t = i + 1;
    int local = g - tab.cum[t];
    if (local >= tab.n[t]) return;
    float v;
    if (*flag) v = ((const float*)tab.in[t])[local];
    else       v = b2f(((const bf16*)tab.in[t])[local]);
    base[g] = v;
}

// ---------- pipeline (fp32 state, bf16 hbX) ----------

__global__ void k_input_proj(const float* __restrict__ nf, const float* __restrict__ Win,
                             const float* __restrict__ bin, float* __restrict__ h) {
    __shared__ float w[FIN * HH];
    __shared__ float bb[HH];
    int tid = threadIdx.x;
    for (int i = tid; i < FIN * HH; i += 256) w[i] = Win[i];
    if (tid < HH) bb[tid] = bin[tid];
    __syncthreads();
    int idx = blockIdx.x * 256 + tid;
    if (idx >= NN * HH) return;
    int n = idx >> 6, j = idx & 63;
    float acc = bb[j];
    const float* row = nf + n * FIN;
#pragma unroll
    for (int k = 0; k < FIN; ++k) acc = fmaf(row[k], w[k * HH + j], acc);
    h[idx] = acc;
}

// hbX[n][j] = ushort4 of bf16( sum_k h[n][k]*bases[b][k][j] ), b=0..3 packed
// block=256 (4 waves), each wave: 4 nodes, all 4 bases; weights from global (L1-hot)
__global__ void k_hb2(const float* __restrict__ h, const float* __restrict__ bases,
                      ushort4* __restrict__ hbX, int doRelu) {
    int tid = threadIdx.x;
    int lane = tid & 63;
    int wv = tid >> 6;
    int n0 = blockIdx.x * 16 + wv * 4;
    float hval[4];
#pragma unroll
    for (int ln = 0; ln < 4; ++ln) {
        float v = h[(long)(n0 + ln) * HH + lane];
        hval[ln] = doRelu ? fmaxf(v, 0.f) : v;
    }
    float acc[4][4];
#pragma unroll
    for (int ln = 0; ln < 4; ++ln)
#pragma unroll
        for (int b = 0; b < NBASE; ++b) acc[ln][b] = 0.f;
    const float* bp = bases + lane;
#pragma unroll 16
    for (int k = 0; k < HH; ++k) {
        float w0 = bp[k * HH];
        float w1 = bp[4096 + k * HH];
        float w2 = bp[8192 + k * HH];
        float w3 = bp[12288 + k * HH];
#pragma unroll
        for (int ln = 0; ln < 4; ++ln) {
            float hv = bcast(hval[ln], k);
            acc[ln][0] = fmaf(hv, w0, acc[ln][0]);
            acc[ln][1] = fmaf(hv, w1, acc[ln][1]);
            acc[ln][2] = fmaf(hv, w2, acc[ln][2]);
            acc[ln][3] = fmaf(hv, w3, acc[ln][3]);
        }
    }
#pragma unroll
    for (int ln = 0; ln < 4; ++ln) {
        ushort4 u;
        u.x = f2bu(acc[ln][0]);
        u.y = f2bu(acc[ln][1]);
        u.z = f2bu(acc[ln][2]);
        u.w = f2bu(acc[ln][3]);
        hbX[(long)(n0 + ln) * HH + lane] = u;
    }
}

// pre[n][j] = sum_k h[n][k]*Wself[k][j] + bself[j]; 8 nodes/wave, readlane bcast
__global__ void k_self2(const float* __restrict__ h, const float* __restrict__ Wself,
                        const float* __restrict__ bself, float* __restrict__ pre,
                        int doRelu) {
    int tid = threadIdx.x;
    int lane = tid & 63;
    int wv = tid >> 6;
    int n0 = blockIdx.x * 32 + wv * 8;
    float hval[8];
#pragma unroll
    for (int ln = 0; ln < 8; ++ln) {
        float v = h[(long)(n0 + ln) * HH + lane];
        hval[ln] = doRelu ? fmaxf(v, 0.f) : v;
    }
    float bb = bself[lane];
    float acc[8];
#pragma unroll
    for (int ln = 0; ln < 8; ++ln) acc[ln] = bb;
#pragma unroll 16
    for (int k = 0; k < HH; ++k) {
        float wk = Wself[k * HH + lane];
#pragma unroll
        for (int ln = 0; ln < 8; ++ln)
            acc[ln] = fmaf(bcast(hval[ln], k), wk, acc[ln]);
    }
#pragma unroll
    for (int ln = 0; ln < 8; ++ln) pre[(long)(n0 + ln) * HH + lane] = acc[ln];
}

// per edge: one ushort4 (4 bf16) load/lane; msg = sum_b c[b]*hb[b]; atomic scatter
#define EPW 8
__global__ void k_edge2(const ushort4* __restrict__ hbX, const int* __restrict__ src,
                        const int* __restrict__ tgt, const int* __restrict__ et,
                        const float* __restrict__ coeffs, float* __restrict__ pre) {
    int lane = threadIdx.x & 63;
    int wid = (blockIdx.x * 256 + threadIdx.x) >> 6;
    int e0 = wid * EPW;
#pragma unroll
    for (int i = 0; i < EPW; ++i) {
        int e = e0 + i;
        if (e >= EE) return;
        int s = src[e], t = tgt[e], r = et[e];
        ushort4 u = hbX[(long)s * HH + lane];
        const float* c = coeffs + r * NBASE;
        float m = c[0] * bu2f(u.x);
        m = fmaf(c[1], bu2f(u.y), m);
        m = fmaf(c[2], bu2f(u.z), m);
        m = fmaf(c[3], bu2f(u.w), m);
        atomicAdd(&pre[(long)t * HH + lane], m);
    }
}

// per-block partial sum & max of relu(h)
__global__ void k_reduce(const float* __restrict__ h, float* __restrict__ psum,
                         float* __restrict__ pmax) {
    __shared__ float ls[256], lm[256];
    int tid = threadIdx.x;
    int j = tid & 63;
    int slot = tid >> 6;
    float s = 0.f, m = -1e30f;
    for (int n = blockIdx.x * 4 + slot; n < NN; n += gridDim.x * 4) {
        float v = fmaxf(h[n * HH + j], 0.f);
        s += v;
        m = fmaxf(m, v);
    }
    ls[tid] = s; lm[tid] = m;
    __syncthreads();
    if (tid < 64) {
        s = ls[tid] + ls[tid + 64] + ls[tid + 128] + ls[tid + 192];
        m = fmaxf(fmaxf(lm[tid], lm[tid + 64]), fmaxf(lm[tid + 128], lm[tid + 192]));
        psum[blockIdx.x * 64 + tid] = s;
        pmax[blockIdx.x * 64 + tid] = m;
    }
}

__global__ void k_final(const float* __restrict__ psum, const float* __restrict__ pmax,
                        int nblocks, const float* __restrict__ Wr1, const float* __restrict__ br1,
                        const float* __restrict__ Wr2, const float* __restrict__ br2,
                        void* __restrict__ out, const int* __restrict__ flag) {
    __shared__ float g[2 * HH];
    __shared__ float tbuf[HH];
    int tid = threadIdx.x;  // 128 threads
    if (tid < 64) {
        float s = 0.f, m = -1e30f;
        for (int i = 0; i < nblocks; ++i) {
            s += psum[i * 64 + tid];
            m = fmaxf(m, pmax[i * 64 + tid]);
        }
        g[tid] = s * (1.0f / NN);
        g[64 + tid] = m;
    }
    __syncthreads();
    if (tid < 64) {
        float acc = br1[tid];
        for (int k = 0; k < 2 * HH; ++k) acc = fmaf(g[k], Wr1[k * HH + tid], acc);
        tbuf[tid] = fmaxf(acc, 0.f);
    }
    __syncthreads();
    float acc = br2[tid];
    for (int k = 0; k < HH; ++k) acc = fmaf(tbuf[k], Wr2[k * EMBD + tid], acc);
    if (*flag) ((float*)out)[tid] = acc;
    else       ((bf16*)out)[tid] = __float2bfloat16(acc);
}

// node_emb: 8 nodes/wave, 128 cols (2/lane), relu on load
__global__ void k_node_emb2(const float* __restrict__ h, const float* __restrict__ Wnp,
                            const float* __restrict__ bnp, void* __restrict__ out,
                            const int* __restrict__ flag) {
    int tid = threadIdx.x;
    int lane = tid & 63;
    int wv = tid >> 6;
    int n0 = blockIdx.x * 32 + wv * 8;
    float hval[8];
#pragma unroll
    for (int ln = 0; ln < 8; ++ln)
        hval[ln] = fmaxf(h[(long)(n0 + ln) * HH + lane], 0.f);
    float b0 = bnp[lane], b1 = bnp[64 + lane];
    float acc0[8], acc1[8];
#pragma unroll
    for (int ln = 0; ln < 8; ++ln) { acc0[ln] = b0; acc1[ln] = b1; }
#pragma unroll 8
    for (int k = 0; k < HH; ++k) {
        float w0 = Wnp[k * EMBD + lane];
        float w1 = Wnp[k * EMBD + 64 + lane];
#pragma unroll
        for (int ln = 0; ln < 8; ++ln) {
            float hv = bcast(hval[ln], k);
            acc0[ln] = fmaf(hv, w0, acc0[ln]);
            acc1[ln] = fmaf(hv, w1, acc1[ln]);
        }
    }
    if (*flag) {
        float* o = (float*)out + EMBD;
#pragma unroll
        for (int ln = 0; ln < 8; ++ln) {
            o[(long)(n0 + ln) * EMBD + lane] = acc0[ln];
            o[(long)(n0 + ln) * EMBD + 64 + lane] = acc1[ln];
        }
    } else {
        bf16* o = (bf16*)out + EMBD;
#pragma unroll
        for (int ln = 0; ln < 8; ++ln) {
            o[(long)(n0 + ln) * EMBD + lane] = __float2bfloat16(acc0[ln]);
            o[(long)(n0 + ln) * EMBD + 64 + lane] = __float2bfloat16(acc1[ln]);
        }
    }
}

extern "C" void kernel_launch(void* const* d_in, const int* in_sizes, int n_in,
                              void* d_out, int out_size, void* d_ws, size_t ws_size,
                              hipStream_t stream) {
    const int* eidx  = (const int*)d_in[1];
    const int* etype = (const int*)d_in[2];
    const int* src = eidx;
    const int* tgt = eidx + EE;

    int* flag = (int*)d_ws;
    float* base = (float*)d_ws + 16;

    const int fidx[17] = {0, 3, 4, 5, 6, 7, 8, 9, 10, 11, 12, 13, 14, 15, 16, 17, 18};
    ConvTab tab;
    float* conv[19];
    int cum = 0;
    for (int t = 0; t < 17; ++t) {
        int i = fidx[t];
        tab.in[t] = d_in[i];
        tab.n[t] = in_sizes[i];
        tab.cum[t] = cum;
        conv[i] = base + cum;
        cum += (in_sizes[i] + 15) & ~15;
    }
    tab.cum[17] = cum;

    k_detect<<<1, 64, 0, stream>>>(d_in[3], flag);
    k_convert_all<<<(cum + 255) / 256, 256, 0, stream>>>(tab, base, flag);

    float* p = base + cum;
    float* hA   = p;  p += NN * HH;
    float* hB   = p;  p += NN * HH;
    float* psum = p;  p += 256 * 64;
    float* pmax = p;  p += 256 * 64;
    ushort4* hbX = (ushort4*)p;          // NN*HH ushort4 = 51.2 MB

    const float* nf      = conv[0];
    const float* Win     = conv[3];
    const float* bin     = conv[4];
    const float* Wself0  = conv[5];
    const float* bself0  = conv[6];
    const float* bases0  = conv[7];
    const float* coeffs0 = conv[8];
    const float* Wself1  = conv[9];
    const float* bself1  = conv[10];
    const float* bases1  = conv[11];
    const float* coeffs1 = conv[12];
    const float* Wr1     = conv[13];
    const float* br1     = conv[14];
    const float* Wr2     = conv[15];
    const float* br2     = conv[16];
    const float* Wnp     = conv[17];
    const float* bnp     = conv[18];

    const int NHB = (NN * HH) / 256;        // 25000
    const int HBB = NN / 16;                // 6250
    const int SMB = NN / 32;                // 3125
    const int EB2 = EE / (EPW * 4);         // 31250

    k_input_proj<<<NHB, 256, 0, stream>>>(nf, Win, bin, hA);

    // layer 0 (input h0 raw — reference has no activation after input proj)
    k_hb2<<<HBB, 256, 0, stream>>>(hA, bases0, hbX, 0);
    k_self2<<<SMB, 256, 0, stream>>>(hA, Wself0, bself0, hB, 0);
    k_edge2<<<EB2, 256, 0, stream>>>(hbX, src, tgt, etype, coeffs0, hB);

    // layer 1 (consumes relu(hB) on the fly)
    k_hb2<<<HBB, 256, 0, stream>>>(hB, bases1, hbX, 1);
    k_self2<<<SMB, 256, 0, stream>>>(hB, Wself1, bself1, hA, 1);
    k_edge2<<<EB2, 256, 0, stream>>>(hbX, src, tgt, etype, coeffs1, hA);

    // readout (relu(hA) on the fly)
    k_reduce<<<256, 256, 0, stream>>>(hA, psum, pmax);
    k_final<<<1, 128, 0, stream>>>(psum, pmax, 256, Wr1, br1, Wr2, br2, d_out, flag);
    k_node_emb2<<<SMB, 256, 0, stream>>>(hA, Wnp, bnp, d_out, flag);
}

// Round 5
// 696.441 us; speedup vs baseline: 2.7791x; 1.2784x over previous
//
#include <hip/hip_runtime.h>
#include <hip/hip_bf16.h>

#define NN 100000
#define EE 1000000
#define FIN 15
#define HH 64
#define EMBD 128
#define RR 13
#define NBASE 4
#define NP 391          // ceil(NN/256) scan blocks

typedef __hip_bfloat16 bf16;

__device__ __forceinline__ float b2f(bf16 x) { return __bfloat162float(x); }
__device__ __forceinline__ float bcast(float v, int l) {
    return __uint_as_float(__builtin_amdgcn_readlane(__float_as_uint(v), l));
}
__device__ __forceinline__ int bcasti(int v, int l) {
    return (int)__builtin_amdgcn_readlane((unsigned)v, l);
}
__device__ __forceinline__ unsigned short f2bu(float f) {
    bf16 t = __float2bfloat16(f);
    return *reinterpret_cast<unsigned short*>(&t);
}
__device__ __forceinline__ float bu2f(unsigned short u) {
    return __uint_as_float((unsigned)u << 16);
}

// ---------- dtype auto-detect ----------
__global__ void k_detect(const void* __restrict__ win, int* __restrict__ flag) {
    int tid = threadIdx.x;
    const bf16* p = (const bf16*)win;
    int cnt = 0;
    for (int i = tid; i < FIN * HH; i += 64) {
        float v = b2f(p[i]);
        if (!(fabsf(v) < 0.3f)) cnt++;
    }
#pragma unroll
    for (int off = 32; off > 0; off >>= 1) cnt += __shfl_down(cnt, off, 64);
    if (tid == 0) *flag = (cnt > 40) ? 1 : 0;
}

// ---------- fused convert ----------
struct ConvTab {
    const void* in[17];
    int n[17];
    int cum[18];
};

__global__ void k_convert_all(ConvTab tab, float* __restrict__ base,
                              const int* __restrict__ flag) {
    int g = blockIdx.x * 256 + threadIdx.x;
    if (g >= tab.cum[17]) return;
    int t = 0;
#pragma unroll
    for (int i = 0; i < 17; ++i) if (g >= tab.cum[i + 1]) t = i + 1;
    int local = g - tab.cum[t];
    if (local >= tab.n[t]) return;
    float v;
    if (*flag) v = ((const float*)tab.in[t])[local];
    else       v = b2f(((const bf16*)tab.in[t])[local]);
    base[g] = v;
}

// ---------- edge counting-sort by target ----------
__global__ void k_zero(int* __restrict__ a, int n) {
    int i = blockIdx.x * 256 + threadIdx.x;
    if (i < n) a[i] = 0;
}

__global__ void k_hist(const int* __restrict__ tgt, int* __restrict__ count,
                       int* __restrict__ rank) {
    int e = blockIdx.x * 256 + threadIdx.x;
    if (e >= EE) return;
    rank[e] = atomicAdd(&count[tgt[e]], 1);
}

// per-block inclusive scan -> exclusive-within-block + block totals
__global__ void k_scan1(const int* __restrict__ count, int* __restrict__ scanned,
                        int* __restrict__ partials) {
    __shared__ int buf[256];
    int tid = threadIdx.x;
    int i = blockIdx.x * 256 + tid;
    int v = (i < NN) ? count[i] : 0;
    buf[tid] = v;
    __syncthreads();
    for (int off = 1; off < 256; off <<= 1) {
        int t = (tid >= off) ? buf[tid - off] : 0;
        __syncthreads();
        buf[tid] += t;
        __syncthreads();
    }
    if (i < NN) scanned[i] = buf[tid] - v;
    if (tid == 255) partials[blockIdx.x] = buf[255];
}

// single-block exclusive scan of the NP block totals (512 threads, padded)
__global__ void k_scan2(int* __restrict__ partials) {
    __shared__ int buf[512];
    int tid = threadIdx.x;
    int v = (tid < NP) ? partials[tid] : 0;
    buf[tid] = v;
    __syncthreads();
    for (int off = 1; off < 512; off <<= 1) {
        int t = (tid >= off) ? buf[tid - off] : 0;
        __syncthreads();
        buf[tid] += t;
        __syncthreads();
    }
    if (tid < NP) partials[tid] = buf[tid] - v;
}

__global__ void k_scatter(const int* __restrict__ src, const int* __restrict__ tgt,
                          const int* __restrict__ et, const int* __restrict__ rank,
                          const int* __restrict__ scanned, const int* __restrict__ partials,
                          int* __restrict__ packed) {
    int e = blockIdx.x * 256 + threadIdx.x;
    if (e >= EE) return;
    int t = tgt[e];
    int pos = scanned[t] + partials[t >> 8] + rank[e];
    packed[pos] = src[e] | (et[e] << 17);
}

// ---------- pipeline ----------

__global__ void k_input_proj(const float* __restrict__ nf, const float* __restrict__ Win,
                             const float* __restrict__ bin, float* __restrict__ h) {
    __shared__ float w[FIN * HH];
    __shared__ float bb[HH];
    int tid = threadIdx.x;
    for (int i = tid; i < FIN * HH; i += 256) w[i] = Win[i];
    if (tid < HH) bb[tid] = bin[tid];
    __syncthreads();
    int idx = blockIdx.x * 256 + tid;
    if (idx >= NN * HH) return;
    int n = idx >> 6, j = idx & 63;
    float acc = bb[j];
    const float* row = nf + n * FIN;
#pragma unroll
    for (int k = 0; k < FIN; ++k) acc = fmaf(row[k], w[k * HH + j], acc);
    h[idx] = acc;
}

// hbX[n][j] = ushort4 of bf16( sum_k h[n][k]*bases[b][k][j] ), b packed in .x..w
__global__ void k_hb2(const float* __restrict__ h, const float* __restrict__ bases,
                      ushort4* __restrict__ hbX, int doRelu) {
    int tid = threadIdx.x;
    int lane = tid & 63;
    int wv = tid >> 6;
    int n0 = blockIdx.x * 16 + wv * 4;
    float hval[4];
#pragma unroll
    for (int ln = 0; ln < 4; ++ln) {
        float v = h[(long)(n0 + ln) * HH + lane];
        hval[ln] = doRelu ? fmaxf(v, 0.f) : v;
    }
    float acc[4][4];
#pragma unroll
    for (int ln = 0; ln < 4; ++ln)
#pragma unroll
        for (int b = 0; b < NBASE; ++b) acc[ln][b] = 0.f;
    const float* bp = bases + lane;
#pragma unroll 16
    for (int k = 0; k < HH; ++k) {
        float w0 = bp[k * HH];
        float w1 = bp[4096 + k * HH];
        float w2 = bp[8192 + k * HH];
        float w3 = bp[12288 + k * HH];
#pragma unroll
        for (int ln = 0; ln < 4; ++ln) {
            float hv = bcast(hval[ln], k);
            acc[ln][0] = fmaf(hv, w0, acc[ln][0]);
            acc[ln][1] = fmaf(hv, w1, acc[ln][1]);
            acc[ln][2] = fmaf(hv, w2, acc[ln][2]);
            acc[ln][3] = fmaf(hv, w3, acc[ln][3]);
        }
    }
#pragma unroll
    for (int ln = 0; ln < 4; ++ln) {
        ushort4 u;
        u.x = f2bu(acc[ln][0]);
        u.y = f2bu(acc[ln][1]);
        u.z = f2bu(acc[ln][2]);
        u.w = f2bu(acc[ln][3]);
        hbX[(long)(n0 + ln) * HH + lane] = u;
    }
}

__global__ void k_self2(const float* __restrict__ h, const float* __restrict__ Wself,
                        const float* __restrict__ bself, float* __restrict__ pre,
                        int doRelu) {
    int tid = threadIdx.x;
    int lane = tid & 63;
    int wv = tid >> 6;
    int n0 = blockIdx.x * 32 + wv * 8;
    float hval[8];
#pragma unroll
    for (int ln = 0; ln < 8; ++ln) {
        float v = h[(long)(n0 + ln) * HH + lane];
        hval[ln] = doRelu ? fmaxf(v, 0.f) : v;
    }
    float bb = bself[lane];
    float acc[8];
#pragma unroll
    for (int ln = 0; ln < 8; ++ln) acc[ln] = bb;
#pragma unroll 16
    for (int k = 0; k < HH; ++k) {
        float wk = Wself[k * HH + lane];
#pragma unroll
        for (int ln = 0; ln < 8; ++ln)
            acc[ln] = fmaf(bcast(hval[ln], k), wk, acc[ln]);
    }
#pragma unroll
    for (int ln = 0; ln < 8; ++ln) pre[(long)(n0 + ln) * HH + lane] = acc[ln];
}

// segmented aggregation: one wave per target node, zero atomics
__global__ void k_edge3(const ushort4* __restrict__ hbX, const int* __restrict__ packed,
                        const int* __restrict__ count, const int* __restrict__ scanned,
                        const int* __restrict__ partials, const float* __restrict__ coeffs,
                        float* __restrict__ pre) {
    int tid = threadIdx.x;
    int lane = tid & 63;
    int t = blockIdx.x * 4 + (tid >> 6);
    if (t >= NN) return;
    int cnt = count[t];
    int s0 = scanned[t] + partials[t >> 8];
    float acc = 0.f;
    for (int base = 0; base < cnt; base += 64) {
        int pk = 0;
        if (base + lane < cnt) pk = packed[s0 + base + lane];
        int m = min(64, cnt - base);
        for (int j = 0; j < m; ++j) {
            int v = bcasti(pk, j);
            int s = v & 0x1FFFF;
            int r = v >> 17;
            ushort4 u = hbX[(long)s * HH + lane];
            const float* c = coeffs + r * NBASE;
            float mm = c[0] * bu2f(u.x);
            mm = fmaf(c[1], bu2f(u.y), mm);
            mm = fmaf(c[2], bu2f(u.z), mm);
            mm = fmaf(c[3], bu2f(u.w), mm);
            acc += mm;
        }
    }
    pre[(long)t * HH + lane] += acc;   // sole writer of node t -> no atomic
}

// stage 1: per-block partial sum & max of relu(h)
__global__ void k_reduce(const float* __restrict__ h, float* __restrict__ psum,
                         float* __restrict__ pmax) {
    __shared__ float ls[256], lm[256];
    int tid = threadIdx.x;
    int j = tid & 63;
    int slot = tid >> 6;
    float s = 0.f, m = -1e30f;
    for (int n = blockIdx.x * 4 + slot; n < NN; n += gridDim.x * 4) {
        float v = fmaxf(h[n * HH + j], 0.f);
        s += v;
        m = fmaxf(m, v);
    }
    ls[tid] = s; lm[tid] = m;
    __syncthreads();
    if (tid < 64) {
        s = ls[tid] + ls[tid + 64] + ls[tid + 128] + ls[tid + 192];
        m = fmaxf(fmaxf(lm[tid], lm[tid + 64]), fmaxf(lm[tid + 128], lm[tid + 192]));
        psum[blockIdx.x * 64 + tid] = s;
        pmax[blockIdx.x * 64 + tid] = m;
    }
}

// stage 2: 256->1 parallel combine; g[0..63]=mean, g[64..127]=max
__global__ void k_reduce2(const float* __restrict__ psum, const float* __restrict__ pmax,
                          float* __restrict__ g) {
    __shared__ float ls[256], lm[256];
    int tid = threadIdx.x;
    int j = tid & 63;
    int slot = tid >> 6;
    float s = 0.f, m = -1e30f;
    for (int i = slot; i < 256; i += 4) {
        s += psum[i * 64 + j];
        m = fmaxf(m, pmax[i * 64 + j]);
    }
    ls[tid] = s; lm[tid] = m;
    __syncthreads();
    if (tid < 64) {
        s = ls[tid] + ls[tid + 64] + ls[tid + 128] + ls[tid + 192];
        m = fmaxf(fmaxf(lm[tid], lm[tid + 64]), fmaxf(lm[tid + 128], lm[tid + 192]));
        g[tid] = s * (1.0f / NN);
        g[64 + tid] = m;
    }
}

__global__ void k_final(const float* __restrict__ g,
                        const float* __restrict__ Wr1, const float* __restrict__ br1,
                        const float* __restrict__ Wr2, const float* __restrict__ br2,
                        void* __restrict__ out, const int* __restrict__ flag) {
    __shared__ float tbuf[HH];
    int tid = threadIdx.x;  // 128 threads
    if (tid < 64) {
        float acc = br1[tid];
#pragma unroll 8
        for (int k = 0; k < 2 * HH; ++k) acc = fmaf(g[k], Wr1[k * HH + tid], acc);
        tbuf[tid] = fmaxf(acc, 0.f);
    }
    __syncthreads();
    float acc = br2[tid];
#pragma unroll 8
    for (int k = 0; k < HH; ++k) acc = fmaf(tbuf[k], Wr2[k * EMBD + tid], acc);
    if (*flag) ((float*)out)[tid] = acc;
    else       ((bf16*)out)[tid] = __float2bfloat16(acc);
}

__global__ void k_node_emb2(const float* __restrict__ h, const float* __restrict__ Wnp,
                            const float* __restrict__ bnp, void* __restrict__ out,
                            const int* __restrict__ flag) {
    int tid = threadIdx.x;
    int lane = tid & 63;
    int wv = tid >> 6;
    int n0 = blockIdx.x * 32 + wv * 8;
    float hval[8];
#pragma unroll
    for (int ln = 0; ln < 8; ++ln)
        hval[ln] = fmaxf(h[(long)(n0 + ln) * HH + lane], 0.f);
    float b0 = bnp[lane], b1 = bnp[64 + lane];
    float acc0[8], acc1[8];
#pragma unroll
    for (int ln = 0; ln < 8; ++ln) { acc0[ln] = b0; acc1[ln] = b1; }
#pragma unroll 8
    for (int k = 0; k < HH; ++k) {
        float w0 = Wnp[k * EMBD + lane];
        float w1 = Wnp[k * EMBD + 64 + lane];
#pragma unroll
        for (int ln = 0; ln < 8; ++ln) {
            float hv = bcast(hval[ln], k);
            acc0[ln] = fmaf(hv, w0, acc0[ln]);
            acc1[ln] = fmaf(hv, w1, acc1[ln]);
        }
    }
    if (*flag) {
        float* o = (float*)out + EMBD;
#pragma unroll
        for (int ln = 0; ln < 8; ++ln) {
            o[(long)(n0 + ln) * EMBD + lane] = acc0[ln];
            o[(long)(n0 + ln) * EMBD + 64 + lane] = acc1[ln];
        }
    } else {
        bf16* o = (bf16*)out + EMBD;
#pragma unroll
        for (int ln = 0; ln < 8; ++ln) {
            o[(long)(n0 + ln) * EMBD + lane] = __float2bfloat16(acc0[ln]);
            o[(long)(n0 + ln) * EMBD + 64 + lane] = __float2bfloat16(acc1[ln]);
        }
    }
}

extern "C" void kernel_launch(void* const* d_in, const int* in_sizes, int n_in,
                              void* d_out, int out_size, void* d_ws, size_t ws_size,
                              hipStream_t stream) {
    const int* eidx  = (const int*)d_in[1];
    const int* etype = (const int*)d_in[2];
    const int* src = eidx;
    const int* tgt = eidx + EE;

    int* flag = (int*)d_ws;
    float* base = (float*)d_ws + 16;

    const int fidx[17] = {0, 3, 4, 5, 6, 7, 8, 9, 10, 11, 12, 13, 14, 15, 16, 17, 18};
    ConvTab tab;
    float* conv[19];
    int cum = 0;
    for (int t = 0; t < 17; ++t) {
        int i = fidx[t];
        tab.in[t] = d_in[i];
        tab.n[t] = in_sizes[i];
        tab.cum[t] = cum;
        conv[i] = base + cum;
        cum += (in_sizes[i] + 15) & ~15;
    }
    tab.cum[17] = cum;

    k_detect<<<1, 64, 0, stream>>>(d_in[3], flag);
    k_convert_all<<<(cum + 255) / 256, 256, 0, stream>>>(tab, base, flag);

    float* p = base + cum;
    float* hA   = p;  p += NN * HH;
    float* hB   = p;  p += NN * HH;
    float* psum = p;  p += 256 * 64;
    float* pmax = p;  p += 256 * 64;
    float* gvec = p;  p += 2 * HH;
    // int-typed sort scratch
    int* count    = (int*)p;           p += NN;
    int* scanned  = (int*)p;           p += NN;
    int* partials = (int*)p;           p += 512;
    int* rank     = (int*)p;           p += EE;
    int* packed   = (int*)p;           p += EE;
    ushort4* hbX  = (ushort4*)p;       // NN*HH ushort4 = 51.2 MB

    const float* nf      = conv[0];
    const float* Win     = conv[3];
    const float* bin     = conv[4];
    const float* Wself0  = conv[5];
    const float* bself0  = conv[6];
    const float* bases0  = conv[7];
    const float* coeffs0 = conv[8];
    const float* Wself1  = conv[9];
    const float* bself1  = conv[10];
    const float* bases1  = conv[11];
    const float* coeffs1 = conv[12];
    const float* Wr1     = conv[13];
    const float* br1     = conv[14];
    const float* Wr2     = conv[15];
    const float* br2     = conv[16];
    const float* Wnp     = conv[17];
    const float* bnp     = conv[18];

    const int NHB = (NN * HH) / 256;   // 25000
    const int HBB = NN / 16;           // 6250
    const int SMB = NN / 32;           // 3125
    const int EB  = (EE + 255) / 256;  // 3907
    const int SEG = NN / 4;            // 25000

    // edge sort by target (reused by both layers)
    k_zero<<<(NN + 255) / 256, 256, 0, stream>>>(count, NN);
    k_hist<<<EB, 256, 0, stream>>>(tgt, count, rank);
    k_scan1<<<NP, 256, 0, stream>>>(count, scanned, partials);
    k_scan2<<<1, 512, 0, stream>>>(partials);
    k_scatter<<<EB, 256, 0, stream>>>(src, tgt, etype, rank, scanned, partials, packed);

    k_input_proj<<<NHB, 256, 0, stream>>>(nf, Win, bin, hA);

    // layer 0
    k_hb2<<<HBB, 256, 0, stream>>>(hA, bases0, hbX, 0);
    k_self2<<<SMB, 256, 0, stream>>>(hA, Wself0, bself0, hB, 0);
    k_edge3<<<SEG, 256, 0, stream>>>(hbX, packed, count, scanned, partials, coeffs0, hB);

    // layer 1 (consumes relu(hB) on the fly)
    k_hb2<<<HBB, 256, 0, stream>>>(hB, bases1, hbX, 1);
    k_self2<<<SMB, 256, 0, stream>>>(hB, Wself1, bself1, hA, 1);
    k_edge3<<<SEG, 256, 0, stream>>>(hbX, packed, count, scanned, partials, coeffs1, hA);

    // readout (relu(hA) on the fly)
    k_reduce<<<256, 256, 0, stream>>>(hA, psum, pmax);
    k_reduce2<<<1, 256, 0, stream>>>(psum, pmax, gvec);
    k_final<<<1, 128, 0, stream>>>(gvec, Wr1, br1, Wr2, br2, d_out, flag);
    k_node_emb2<<<SMB, 256, 0, stream>>>(hA, Wnp, bnp, d_out, flag);
}